// Round 17
// baseline (936.835 us; speedup 1.0000x reference)
//
#include <hip/hip_runtime.h>

// HunyuanVideoDoubleStreamBlock on MI355X (gfx950).
// Needs ws_size >= ~87 MB.

#define SI 1024
#define ST 256
#define SS 1280
#define CC 3072
#define NH 24
#define DH 128
#define MLPD 12288
#define EPSF 1e-6f
#define SCALEF 0.08838834764831845f   // 1/sqrt(128)

typedef __attribute__((ext_vector_type(4))) float f32x4;
typedef __attribute__((ext_vector_type(8))) __bf16 bf16x8;
typedef unsigned short u16;
typedef unsigned int u32;

__device__ __forceinline__ u16 f2bf(float x) {
    union { float f; u32 u; } v; v.f = x;
    u32 r = v.u + 0x7FFFu + ((v.u >> 16) & 1u);   // RNE
    return (u16)(r >> 16);
}
__device__ __forceinline__ float bf2f(u16 x) {
    union { u32 u; float f; } v; v.u = ((u32)x) << 16; return v.f;
}

// 16B-chunk swizzle (validated numerically R6-R16).
__device__ __forceinline__ int gsw(int r) {
    return ((r >> 2) & 7) ^ ((r & 3) << 1);
}

// ---------------------------------------------------------------------------
// K0: sv = silu(vec); mod = sv @ mod_w + mod_b  (both streams)
// ---------------------------------------------------------------------------
__global__ __launch_bounds__(256) void k_modvec(
    const float* __restrict__ vec,
    const float* __restrict__ wi, const float* __restrict__ bi,
    const float* __restrict__ wt, const float* __restrict__ bt,
    float* __restrict__ mi, float* __restrict__ mt)
{
    __shared__ float sv[CC];
    __shared__ float part[7][128];
    int t = threadIdx.x;
    for (int i = t; i < CC; i += 256) {
        float x = vec[i];
        sv[i] = x / (1.f + __expf(-x));
    }
    __syncthreads();
    int gc = blockIdx.x;
    int strm = gc >= 144;
    const float* W  = strm ? wt : wi;
    const float* Bv = strm ? bt : bi;
    float* out      = strm ? mt : mi;
    int c0 = (gc % 144) * 128 + 4 * (t & 31);
    int g  = t >> 5;
    const float* wp  = W + (size_t)(g * 384) * (6 * CC) + c0;
    const float* svp = sv + g * 384;
    f32x4 acc = {0.f, 0.f, 0.f, 0.f};
    for (int r = 0; r < 384; ++r) {
        f32x4 wr = *(const f32x4*)(wp + (size_t)r * (6 * CC));
        float s = svp[r];
        acc.x += wr.x * s; acc.y += wr.y * s; acc.z += wr.z * s; acc.w += wr.w * s;
    }
    int li = t & 31;
    if (g > 0) *(f32x4*)&part[g - 1][li * 4] = acc;
    __syncthreads();
    if (g == 0) {
#pragma unroll
        for (int i = 0; i < 7; ++i) {
            f32x4 p = *(const f32x4*)&part[i][li * 4];
            acc.x += p.x; acc.y += p.y; acc.z += p.z; acc.w += p.w;
        }
        f32x4 bb = *(const f32x4*)(Bv + c0);
        acc.x += bb.x; acc.y += bb.y; acc.z += bb.z; acc.w += bb.w;
        *(f32x4*)(out + c0) = acc;
    }
}

// ---------------------------------------------------------------------------
// K1: per-row LayerNorm + modulate -> bf16. Merged streams: r<SI img, else txt.
// ---------------------------------------------------------------------------
__global__ __launch_bounds__(256) void k_lnmod(
    const float* __restrict__ xi, const float* __restrict__ xt,
    const float* __restrict__ shi, const float* __restrict__ sci,
    const float* __restrict__ sht, const float* __restrict__ sct,
    u16* __restrict__ out)
{
    int r = blockIdx.x;
    bool ts = r >= SI;
    const float* xp = ts ? (xt + (size_t)(r - SI) * CC) : (xi + (size_t)r * CC);
    const float* shift = ts ? sht : shi;
    const float* scale = ts ? sct : sci;
    u16* op = out + (size_t)r * CC;
    int t = threadIdx.x;
    float4 v[3];
    float s = 0.f, q = 0.f;
#pragma unroll
    for (int j = 0; j < 3; ++j) {
        v[j] = *(const float4*)(xp + j * 1024 + t * 4);
        s += v[j].x + v[j].y + v[j].z + v[j].w;
        q += v[j].x * v[j].x + v[j].y * v[j].y + v[j].z * v[j].z + v[j].w * v[j].w;
    }
#pragma unroll
    for (int m = 32; m; m >>= 1) { s += __shfl_xor(s, m); q += __shfl_xor(q, m); }
    __shared__ float red[8];
    int w = t >> 6;
    if ((t & 63) == 0) { red[w] = s; red[4 + w] = q; }
    __syncthreads();
    s = red[0] + red[1] + red[2] + red[3];
    q = red[4] + red[5] + red[6] + red[7];
    float mean = s * (1.f / CC);
    float var  = q * (1.f / CC) - mean * mean;
    float inv  = rsqrtf(var + EPSF);
#pragma unroll
    for (int j = 0; j < 3; ++j) {
        int c0 = j * 1024 + t * 4;
        float4 sh = *(const float4*)(shift + c0);
        float4 sc = *(const float4*)(scale + c0);
        ushort4 o;
        o.x = f2bf((v[j].x - mean) * inv * (1.f + sc.x) + sh.x);
        o.y = f2bf((v[j].y - mean) * inv * (1.f + sc.y) + sh.y);
        o.z = f2bf((v[j].z - mean) * inv * (1.f + sc.z) + sh.z);
        o.w = f2bf((v[j].w - mean) * inv * (1.f + sc.w) + sh.w);
        *(ushort4*)(op + c0) = o;
    }
}

// ---------------------------------------------------------------------------
// K2a: GEMM with DIRECT-A fragments (no A LDS). BM=BN=256, BK=64, 512 thr /
// 8 waves (2m x 4n), wave tile 128x64. A-fragments (bf16, fragment-compatible
// global layout) are read straight from global (L1-cached, 4x wave reuse).
// LDS holds only B (2 x 32 KB). Barrier guards only B ds_write->ds_read.
//   V=1: out bf16 = gelu_tanh(val+bias) ; V=2: out bf16 = val+bias
// ---------------------------------------------------------------------------
template <int V>
__global__ __launch_bounds__(512, 2) void k_gemmA(
    const u16* __restrict__ A,
    const float* __restrict__ Wi, const float* __restrict__ Wt,
    const float* __restrict__ bi, const float* __restrict__ bt,
    void* __restrict__ outv, int MBI, int N, int K, int lda)
{
    __shared__ u16 lB[2][256 * 64];
    int t = threadIdx.x;
    int m0 = blockIdx.y * 256;
    int n0 = blockIdx.x * 256;
    bool txts = (blockIdx.y >= (unsigned)MBI);
    const float* W = txts ? Wt : Wi;

    int w = __builtin_amdgcn_readfirstlane(t >> 6);
    int lane = t & 63;
    int wm = (w >> 2) * 128, wn = (w & 3) * 64;
    int lr = lane & 15, lg = lane >> 4;

    f32x4 acc[8][4];
#pragma unroll
    for (int i = 0; i < 8; ++i)
#pragma unroll
        for (int j = 0; j < 4; ++j) acc[i][j] = (f32x4){0.f, 0.f, 0.f, 0.f};

    const int bn4 = 4 * (t & 63);
    const int bk  = 8 * w;
    f32x4 fb[8];
    const int NT = K >> 6;

    const float* bptr = W + (size_t)bk * N + n0 + bn4;
    // per-thread A fragment base: row (m0+wm+lr), col lg*8
    const u16* aptr = A + (size_t)(m0 + wm + lr) * lda + lg * 8;

    auto LOADB = [&]() {
#pragma unroll
        for (int i = 0; i < 8; ++i)
            fb[i] = *(const f32x4*)(bptr + (size_t)i * N);
        bptr += (size_t)64 * N;
    };
    auto CVTWR = [&](int buf) {
#pragma unroll
        for (int j = 0; j < 4; ++j) {
            int n = bn4 + j;
            union { uint4 q; __bf16 h[8]; } u;
#pragma unroll
            for (int i = 0; i < 8; ++i) u.h[i] = (__bf16)fb[i][j];
            int cp = (bk >> 3) ^ gsw(n);
            *(uint4*)&lB[buf][n * 64 + cp * 8] = u.q;
        }
    };
    auto MFMAP = [&](int buf) {
#pragma unroll
        for (int ks = 0; ks < 2; ++ks) {
            bf16x8 bv[4];
#pragma unroll
            for (int j = 0; j < 4; ++j) {
                int n = wn + j * 16 + lr;
                bv[j] = *(const bf16x8*)&lB[buf][n * 64 + (((ks * 4 + lg) ^ gsw(n)) * 8)];
            }
            // issue all 8 A-fragment global loads for this ks up front
            bf16x8 af0[4], af1[4];
#pragma unroll
            for (int i2 = 0; i2 < 4; ++i2)
                af0[i2] = *(const bf16x8*)(aptr + (size_t)(i2 * 16) * lda + ks * 32);
#pragma unroll
            for (int i2 = 0; i2 < 4; ++i2)
                af1[i2] = *(const bf16x8*)(aptr + (size_t)(64 + i2 * 16) * lda + ks * 32);
            __builtin_amdgcn_s_setprio(1);
#pragma unroll
            for (int i2 = 0; i2 < 4; ++i2)
#pragma unroll
                for (int j = 0; j < 4; ++j)
                    acc[i2][j] = __builtin_amdgcn_mfma_f32_16x16x32_bf16(
                        af0[i2], bv[j], acc[i2][j], 0, 0, 0);
#pragma unroll
            for (int i2 = 0; i2 < 4; ++i2)
#pragma unroll
                for (int j = 0; j < 4; ++j)
                    acc[4 + i2][j] = __builtin_amdgcn_mfma_f32_16x16x32_bf16(
                        af1[i2], bv[j], acc[4 + i2][j], 0, 0, 0);
            __builtin_amdgcn_s_setprio(0);
        }
        aptr += 64;   // advance one K-tile
    };

    // ---- prologue: B(0) -> lB[0]; fb <- B(1)
    LOADB();
    CVTWR(0);                       // auto-waits B(0)
    if (NT > 1) LOADB();            // fb <- B(1), in flight
    asm volatile("s_waitcnt lgkmcnt(0)" ::: "memory");
    __builtin_amdgcn_s_barrier();
    __builtin_amdgcn_sched_barrier(0);

    int cur = 0;
    for (int kt = 0; kt < NT; ++kt) {
        bool s1 = kt + 1 < NT;
        bool s2 = kt + 2 < NT;
        if (s1) CVTWR(cur ^ 1);      // B(kt+1): cvt (auto-waits fb) + ds_write
        if (s2) LOADB();             // fb <- B(kt+2), stays in flight
        MFMAP(cur);                  // bv from lB[cur]; A direct from global
        if (s1) {
            asm volatile("s_waitcnt lgkmcnt(0)" ::: "memory");
            __builtin_amdgcn_s_barrier();
            __builtin_amdgcn_sched_barrier(0);
        }
        cur ^= 1;
    }

    // ---- epilogue
    const float* Bb = txts ? bt : bi;
#pragma unroll
    for (int i = 0; i < 8; ++i) {
#pragma unroll
        for (int j = 0; j < 4; ++j) {
            int col = n0 + wn + j * 16 + lr;
            float bvv = Bb[col];
#pragma unroll
            for (int e = 0; e < 4; ++e) {
                int row = m0 + wm + i * 16 + lg * 4 + e;
                float val = acc[i][j][e] + bvv;
                if (V == 1) {
                    float g = 0.5f * val * (1.f + tanhf(0.7978845608028654f * (val + 0.044715f * val * val * val)));
                    ((u16*)outv)[(size_t)row * N + col] = f2bf(g);
                } else {
                    ((u16*)outv)[(size_t)row * N + col] = f2bf(val);
                }
            }
        }
    }
}

// ---------------------------------------------------------------------------
// K2: rolled 2-phase GEMM with glds-A (R16-proven), BM=256 x BN=128 (V=3).
// ---------------------------------------------------------------------------
template <int V>
__global__ __launch_bounds__(512, 2) void k_gemm(
    const u16* __restrict__ A,
    const float* __restrict__ Wi, const float* __restrict__ Wt,
    const float* __restrict__ bi, const float* __restrict__ bt,
    void* __restrict__ outv, int MBI, int N, int K, int lda)
{
    constexpr int BM = 256, BN = 128;
    __shared__ u16 lA[2][BM * 64];
    __shared__ u16 lB[2][BN * 64];
    int t = threadIdx.x;
    int m0 = blockIdx.y * BM;
    int n0 = blockIdx.x * BN;
    bool txts = (blockIdx.y >= (unsigned)MBI);
    const float* W = txts ? Wt : Wi;
    const size_t koff = (size_t)blockIdx.z * K;

    int w = __builtin_amdgcn_readfirstlane(t >> 6);
    int lane = t & 63;
    int wm = (w >> 1) * 64, wn = (w & 1) * 64;
    int lr = lane & 15, lg = lane >> 4;

    f32x4 acc[4][4];
#pragma unroll
    for (int i = 0; i < 4; ++i)
#pragma unroll
        for (int j = 0; j < 4; ++j) acc[i][j] = (f32x4){0.f, 0.f, 0.f, 0.f};

    const int bn4 = 4 * (t & 31);
    const int bk  = 4 * (t >> 5);
    f32x4 fb[4];
    const int NT = K >> 6;

    const float* bptr = W + (koff + bk) * (size_t)N + n0 + bn4;
    const int arow = t >> 3;
    const int acsw = ((t & 7) ^ gsw(arow)) * 8;
    const u16* aptr = A + (size_t)(m0 + arow) * lda + koff + acsw;

    auto LOADB = [&]() {
#pragma unroll
        for (int i = 0; i < 4; ++i)
            fb[i] = *(const f32x4*)(bptr + (size_t)i * N);
        bptr += (size_t)64 * N;
    };
    auto GLDSA = [&](int buf) {
#pragma unroll
        for (int i = 0; i < 4; ++i) {
            const u16* gp = aptr + (size_t)(i * 64) * lda;
            u16* lp = &lA[buf][(i * 512 + t) * 8];
            __builtin_amdgcn_global_load_lds(
                (const __attribute__((address_space(1))) void*)gp,
                (__attribute__((address_space(3))) void*)lp, 16, 0, 0);
        }
        aptr += 64;
    };
    auto CVTWR = [&](int buf) {
#pragma unroll
        for (int j = 0; j < 4; ++j) {
            int n = bn4 + j;
            union { uint2 q; __bf16 h[4]; } u;
#pragma unroll
            for (int i = 0; i < 4; ++i) u.h[i] = (__bf16)fb[i][j];
            int cp = (bk >> 3) ^ gsw(n);
            *(uint2*)&lB[buf][n * 64 + cp * 8 + (bk & 4)] = u.q;
        }
    };
    auto MFMAP = [&](int buf) {
#pragma unroll
        for (int ks = 0; ks < 2; ++ks) {
            bf16x8 bv[4];
#pragma unroll
            for (int j = 0; j < 4; ++j) {
                int n = wn + j * 16 + lr;
                bv[j] = *(const bf16x8*)&lB[buf][n * 64 + (((ks * 4 + lg) ^ gsw(n)) * 8)];
            }
            bf16x8 af[4];
#pragma unroll
            for (int i2 = 0; i2 < 4; ++i2) {
                int m = wm + i2 * 16 + lr;
                af[i2] = *(const bf16x8*)&lA[buf][m * 64 + (((ks * 4 + lg) ^ gsw(m)) * 8)];
            }
            __builtin_amdgcn_s_setprio(1);
#pragma unroll
            for (int i2 = 0; i2 < 4; ++i2)
#pragma unroll
                for (int j = 0; j < 4; ++j)
                    acc[i2][j] = __builtin_amdgcn_mfma_f32_16x16x32_bf16(
                        af[i2], bv[j], acc[i2][j], 0, 0, 0);
            __builtin_amdgcn_s_setprio(0);
        }
    };

    LOADB();
    GLDSA(0);
    CVTWR(0);
    if (NT > 1) LOADB();
    asm volatile("s_waitcnt vmcnt(4) lgkmcnt(0)" ::: "memory");
    __builtin_amdgcn_s_barrier();
    __builtin_amdgcn_sched_barrier(0);

    int cur = 0;
    for (int kt = 0; kt < NT; ++kt) {
        bool s1 = kt + 1 < NT;
        bool s2 = kt + 2 < NT;
        if (s1) {
            GLDSA(cur ^ 1);
            CVTWR(cur ^ 1);
        }
        if (s2) LOADB();
        MFMAP(cur);
        if (s1) {
            if (s2) asm volatile("s_waitcnt vmcnt(4) lgkmcnt(0)" ::: "memory");
            else    asm volatile("s_waitcnt vmcnt(0) lgkmcnt(0)" ::: "memory");
            __builtin_amdgcn_s_barrier();
            __builtin_amdgcn_sched_barrier(0);
        }
        cur ^= 1;
    }

    int MT = gridDim.y * BM;
#pragma unroll
    for (int i = 0; i < 4; ++i) {
#pragma unroll
        for (int j = 0; j < 4; ++j) {
            int col = n0 + wn + j * 16 + lr;
#pragma unroll
            for (int e = 0; e < 4; ++e) {
                int row = m0 + wm + i * 16 + lg * 4 + e;
                ((float*)outv)[((size_t)blockIdx.z * MT + row) * N + col] = acc[i][j][e];
            }
        }
    }
}

// ---------------------------------------------------------------------------
// K2b: split-K reduce + bias + gate + residual.  out = base + (p0+p1+b)*g
// ---------------------------------------------------------------------------
__global__ __launch_bounds__(256) void k_red(
    const float* __restrict__ p,
    const float* __restrict__ bi, const float* __restrict__ bt,
    const float* __restrict__ gi, const float* __restrict__ gt,
    const float* __restrict__ basei, const float* __restrict__ baset,
    float* __restrict__ out)
{
    int idx4 = blockIdx.x * 256 + threadIdx.x;
    size_t idx = (size_t)idx4 * 4;
    const size_t MN = (size_t)SS * CC;
    int r = idx4 / 768;
    int c = (idx4 - r * 768) * 4;
    bool ts = r >= SI;
    float4 v0 = *(const float4*)(p + idx);
    float4 v1 = *(const float4*)(p + MN + idx);
    float4 bb = *(const float4*)((ts ? bt : bi) + c);
    float4 gg = *(const float4*)((ts ? gt : gi) + c);
    const float* bp = ts ? (baset + (size_t)(r - SI) * CC + c) : (basei + (size_t)r * CC + c);
    float4 ba = *(const float4*)bp;
    float4 o;
    o.x = ba.x + (v0.x + v1.x + bb.x) * gg.x;
    o.y = ba.y + (v0.y + v1.y + bb.y) * gg.y;
    o.z = ba.z + (v0.z + v1.z + bb.z) * gg.z;
    o.w = ba.w + (v0.w + v1.w + bb.w) * gg.w;
    *(float4*)(out + idx) = o;
}

// ---------------------------------------------------------------------------
// K2c: split-K reduce + bias + gate + residual, FUSED with LayerNorm+mod.
// ---------------------------------------------------------------------------
__global__ __launch_bounds__(256) void k_redln(
    const float* __restrict__ p,
    const float* __restrict__ bi, const float* __restrict__ bt,
    const float* __restrict__ gi, const float* __restrict__ gt,
    const float* __restrict__ basei, const float* __restrict__ baset,
    const float* __restrict__ shi, const float* __restrict__ sci,
    const float* __restrict__ sht, const float* __restrict__ sct,
    float* __restrict__ out, u16* __restrict__ xm)
{
    int r = blockIdx.x;
    int t = threadIdx.x;
    bool ts = r >= SI;
    const size_t MN = (size_t)SS * CC;
    const float* b  = ts ? bt : bi;
    const float* g  = ts ? gt : gi;
    const float* base = ts ? (baset + (size_t)(r - SI) * CC) : (basei + (size_t)r * CC);
    const float* p0 = p + (size_t)r * CC;
    const float* p1 = p0 + MN;
    float* op = out + (size_t)r * CC;
    u16*   xp = xm + (size_t)r * CC;

    float4 v[3];
    float s = 0.f, q = 0.f;
#pragma unroll
    for (int j = 0; j < 3; ++j) {
        int c0 = j * 1024 + t * 4;
        float4 a0 = *(const float4*)(p0 + c0);
        float4 a1 = *(const float4*)(p1 + c0);
        float4 bb = *(const float4*)(b + c0);
        float4 gg = *(const float4*)(g + c0);
        float4 ba = *(const float4*)(base + c0);
        float4 o;
        o.x = ba.x + (a0.x + a1.x + bb.x) * gg.x;
        o.y = ba.y + (a0.y + a1.y + bb.y) * gg.y;
        o.z = ba.z + (a0.z + a1.z + bb.z) * gg.z;
        o.w = ba.w + (a0.w + a1.w + bb.w) * gg.w;
        *(float4*)(op + c0) = o;
        v[j] = o;
        s += o.x + o.y + o.z + o.w;
        q += o.x * o.x + o.y * o.y + o.z * o.z + o.w * o.w;
    }
#pragma unroll
    for (int m = 32; m; m >>= 1) { s += __shfl_xor(s, m); q += __shfl_xor(q, m); }
    __shared__ float red[8];
    int w = t >> 6;
    if ((t & 63) == 0) { red[w] = s; red[4 + w] = q; }
    __syncthreads();
    s = red[0] + red[1] + red[2] + red[3];
    q = red[4] + red[5] + red[6] + red[7];
    float mean = s * (1.f / CC);
    float var  = q * (1.f / CC) - mean * mean;
    float inv  = rsqrtf(var + EPSF);
    const float* sh = ts ? sht : shi;
    const float* sc = ts ? sct : sci;
#pragma unroll
    for (int j = 0; j < 3; ++j) {
        int c0 = j * 1024 + t * 4;
        float4 shv = *(const float4*)(sh + c0);
        float4 scv = *(const float4*)(sc + c0);
        ushort4 o;
        o.x = f2bf((v[j].x - mean) * inv * (1.f + scv.x) + shv.x);
        o.y = f2bf((v[j].y - mean) * inv * (1.f + scv.y) + shv.y);
        o.z = f2bf((v[j].z - mean) * inv * (1.f + scv.z) + shv.z);
        o.w = f2bf((v[j].w - mean) * inv * (1.f + scv.w) + shv.w);
        *(ushort4*)(xp + c0) = o;
    }
}

// ---------------------------------------------------------------------------
// K3: qkv epilogue: RMSNorm(q,k)+RoPE(img)+scale(q), pack to [h][s][d] bf16.
// ---------------------------------------------------------------------------
__global__ __launch_bounds__(256) void k_pack(
    const u16* __restrict__ qkv,
    const float* __restrict__ iqn, const float* __restrict__ ikn,
    const float* __restrict__ tqn, const float* __restrict__ tkn,
    const float* __restrict__ fc, const float* __restrict__ fs,
    u16* __restrict__ qpk, u16* __restrict__ kpk, u16* __restrict__ vpk)
{
    int wid = blockIdx.x * 4 + (threadIdx.x >> 6);
    int lane = threadIdx.x & 63;
    int s = wid / 72;
    int wh = wid % 72;
    int which = wh / 24;
    int h = wh % 24;
    int d = lane * 2;
    const u16* src = qkv + (size_t)s * 9216 + which * 3072 + h * 128 + d;
    ushort2 xv = *(const ushort2*)src;
    float x0 = bf2f(xv.x), x1 = bf2f(xv.y);
    float y0 = x0, y1 = x1;
    if (which < 2) {
        float ssq = x0 * x0 + x1 * x1;
#pragma unroll
        for (int m = 32; m; m >>= 1) ssq += __shfl_xor(ssq, m);
        float inv = rsqrtf(ssq * (1.f / 128.f) + EPSF);
        bool isimg = (s < SI);
        const float* wv = (which == 0) ? (isimg ? iqn : tqn) : (isimg ? ikn : tkn);
        y0 = x0 * inv * wv[d];
        y1 = x1 * inv * wv[d + 1];
        if (isimg) {
            float c0 = fc[s * 128 + d], c1 = fc[s * 128 + d + 1];
            float s0 = fs[s * 128 + d], s1 = fs[s * 128 + d + 1];
            float r0 = y0 * c0 - y1 * s0;
            float r1 = y1 * c1 + y0 * s1;
            y0 = r0; y1 = r1;
        }
        if (which == 0) { y0 *= SCALEF; y1 *= SCALEF; }
    }
    u16* dst = (which == 0) ? qpk : (which == 1) ? kpk : vpk;
    ushort2 o; o.x = f2bf(y0); o.y = f2bf(y1);
    *(ushort2*)(dst + ((size_t)h * SS + s) * 128 + d) = o;
}

// ---------------------------------------------------------------------------
// K4: flash attention. grid (10 q-tiles, 24 heads) x 512 (8 waves, 16 q/wave).
// ---------------------------------------------------------------------------
__global__ __launch_bounds__(512, 1) void k_attn(
    const u16* __restrict__ qpk, const u16* __restrict__ kpk,
    const u16* __restrict__ vpk, u16* __restrict__ o)
{
    __shared__ u16 lK[128 * 136];
    __shared__ u16 lV[128 * 136];
    __shared__ u16 lP[128 * 136];
    int h = blockIdx.y;
    int q0 = blockIdx.x * 128;
    int t = threadIdx.x, w = t >> 6, lane = t & 63;
    int lr = lane & 15, lg = lane >> 4;
    const u16* qh = qpk + (size_t)h * SS * 128;
    const u16* kh = kpk + (size_t)h * SS * 128;
    const u16* vh = vpk + (size_t)h * SS * 128;

    bf16x8 aq[4];
#pragma unroll
    for (int kk = 0; kk < 4; ++kk)
        aq[kk] = *(const bf16x8*)(qh + (size_t)(q0 + w * 16 + lr) * 128 + kk * 32 + lg * 8);

    const f32x4 fz = {0.f, 0.f, 0.f, 0.f};
    f32x4 oa[8];
#pragma unroll
    for (int j = 0; j < 8; ++j) oa[j] = fz;
    float mrow[4], lrow[4];
#pragma unroll
    for (int e = 0; e < 4; ++e) { mrow[e] = -1e30f; lrow[e] = 0.f; }

    for (int kt = 0; kt < 10; ++kt) {
        int t0 = kt * 128;
        __syncthreads();
#pragma unroll
        for (int it = 0; it < 4; ++it) {
            int c = it * 512 + t;
            int row = c >> 4, part = c & 15;
            uint4 d4 = *(const uint4*)(kh + (size_t)(t0 + row) * 128 + part * 8);
            *(uint4*)(&lK[row * 136 + part * 8]) = d4;
        }
#pragma unroll
        for (int it = 0; it < 2; ++it) {
            int c = it * 512 + t;
            int pr = c >> 4;
            int tt = pr * 2;
            int k = c & 15;
            int d0 = k * 8;
            uint4 a = *(const uint4*)(vh + (size_t)(t0 + tt) * 128 + d0);
            uint4 b = *(const uint4*)(vh + (size_t)(t0 + tt + 1) * 128 + d0);
            const u16* a16 = (const u16*)&a;
            const u16* b16 = (const u16*)&b;
            int ts = tt ^ ((k & 7) << 3);
#pragma unroll
            for (int j = 0; j < 8; ++j) {
                ushort2 pv; pv.x = a16[j]; pv.y = b16[j];
                *(ushort2*)(&lV[(d0 + j) * 136 + ts]) = pv;
            }
        }
        __syncthreads();
        f32x4 sa[8];
#pragma unroll
        for (int j = 0; j < 8; ++j) sa[j] = fz;
#pragma unroll
        for (int kk = 0; kk < 4; ++kk) {
            bf16x8 bk[8];
#pragma unroll
            for (int ni = 0; ni < 8; ++ni)
                bk[ni] = *(const bf16x8*)(&lK[(ni * 16 + lr) * 136 + kk * 32 + lg * 8]);
            __builtin_amdgcn_s_setprio(1);
#pragma unroll
            for (int ni = 0; ni < 8; ++ni)
                sa[ni] = __builtin_amdgcn_mfma_f32_16x16x32_bf16(aq[kk], bk[ni], sa[ni], 0, 0, 0);
            __builtin_amdgcn_s_setprio(0);
        }
#pragma unroll
        for (int e = 0; e < 4; ++e) {
            float mx = sa[0][e];
#pragma unroll
            for (int ni = 1; ni < 8; ++ni) mx = fmaxf(mx, sa[ni][e]);
#pragma unroll
            for (int msk = 1; msk < 16; msk <<= 1) mx = fmaxf(mx, __shfl_xor(mx, msk));
            float mnew = fmaxf(mrow[e], mx);
            float esc = __expf(mrow[e] - mnew);
            mrow[e] = mnew;
            float rsum = 0.f;
#pragma unroll
            for (int ni = 0; ni < 8; ++ni) {
                float p = __expf(sa[ni][e] - mnew);
                sa[ni][e] = p;
                rsum += p;
            }
#pragma unroll
            for (int msk = 1; msk < 16; msk <<= 1) rsum += __shfl_xor(rsum, msk);
            lrow[e] = lrow[e] * esc + rsum;
#pragma unroll
            for (int nd = 0; nd < 8; ++nd) oa[nd][e] *= esc;
        }
#pragma unroll
        for (int ni = 0; ni < 8; ++ni)
#pragma unroll
            for (int e = 0; e < 4; ++e)
                lP[(w * 16 + lg * 4 + e) * 136 + ni * 16 + lr] = f2bf(sa[ni][e]);
#pragma unroll
        for (int kk = 0; kk < 4; ++kk) {
            bf16x8 pa, vb[8];
            pa = *(const bf16x8*)(&lP[(w * 16 + lr) * 136 + kk * 32 + lg * 8]);
#pragma unroll
            for (int nd = 0; nd < 8; ++nd) {
                int d = nd * 16 + lr;
                int ch = (kk * 4 + lg) ^ ((d >> 3) & 7);
                vb[nd] = *(const bf16x8*)(&lV[d * 136 + ch * 8]);
            }
            __builtin_amdgcn_s_setprio(1);
#pragma unroll
            for (int nd = 0; nd < 8; ++nd)
                oa[nd] = __builtin_amdgcn_mfma_f32_16x16x32_bf16(pa, vb[nd], oa[nd], 0, 0, 0);
            __builtin_amdgcn_s_setprio(0);
        }
    }
#pragma unroll
    for (int nd = 0; nd < 8; ++nd) {
#pragma unroll
        for (int e = 0; e < 4; ++e) {
            int row = q0 + w * 16 + lg * 4 + e;
            int col = h * 128 + nd * 16 + lr;
            o[(size_t)row * CC + col] = f2bf(oa[nd][e] / lrow[e]);
        }
    }
}

// ---------------------------------------------------------------------------
extern "C" void kernel_launch(void* const* d_in, const int* in_sizes, int n_in,
                              void* d_out, int out_size, void* d_ws, size_t ws_size,
                              hipStream_t stream)
{
    const float* img  = (const float*)d_in[0];
    const float* txt  = (const float*)d_in[1];
    const float* vec  = (const float*)d_in[2];
    const float* fc   = (const float*)d_in[3];
    const float* fs   = (const float*)d_in[4];
    const float* i_mod_w = (const float*)d_in[5];
    const float* i_mod_b = (const float*)d_in[6];
    const float* i_qkv_w = (const float*)d_in[7];
    const float* i_qkv_b = (const float*)d_in[8];
    const float* i_qn  = (const float*)d_in[9];
    const float* i_kn  = (const float*)d_in[10];
    const float* i_pw  = (const float*)d_in[11];
    const float* i_pb  = (const float*)d_in[12];
    const float* i_f1w = (const float*)d_in[13];
    const float* i_f1b = (const float*)d_in[14];
    const float* i_f2w = (const float*)d_in[15];
    const float* i_f2b = (const float*)d_in[16];
    const float* t_mod_w = (const float*)d_in[17];
    const float* t_mod_b = (const float*)d_in[18];
    const float* t_qkv_w = (const float*)d_in[19];
    const float* t_qkv_b = (const float*)d_in[20];
    const float* t_qn  = (const float*)d_in[21];
    const float* t_kn  = (const float*)d_in[22];
    const float* t_pw  = (const float*)d_in[23];
    const float* t_pb  = (const float*)d_in[24];
    const float* t_f1w = (const float*)d_in[25];
    const float* t_f1b = (const float*)d_in[26];
    const float* t_f2w = (const float*)d_in[27];
    const float* t_f2b = (const float*)d_in[28];

    char* ws = (char*)d_ws;
    float* mod_i = (float*)(ws + 0);                 // 6*3072 f32
    float* mod_t = (float*)(ws + 73728);
    u16*   xmod  = (u16*)(ws + 147456);              // [1280][3072] bf16
    u16*   qkvb  = (u16*)(ws + 8011776);             // [1280][9216] bf16
    u16*   qpk   = (u16*)(ws + 55197696);            // [24][1280][128] bf16
    u16*   kpk   = (u16*)(ws + 63062016);
    u16*   vpk   = (u16*)(ws + 70926336);
    u16*   obuf  = (u16*)(ws + 78790656);            // [1280][3072] bf16
    u16*   hbuf  = (u16*)(ws + 8011776);             // reuse qkvb: [1280][12288] bf16
    float* pbufP = (float*)(ws + 8011776);           // proj partials [2][1280][3072] f32
    float* pbufF = (float*)(ws + 39469056);          // f2 partials   [2][1280][3072] f32

    float* out_img = (float*)d_out;
    float* out_txt = out_img + (size_t)SI * CC;

    k_modvec<<<288, 256, 0, stream>>>(vec, i_mod_w, i_mod_b, t_mod_w, t_mod_b, mod_i, mod_t);

    k_lnmod<<<SS, 256, 0, stream>>>(img, txt, mod_i + 0, mod_i + 3072,
                                    mod_t + 0, mod_t + 3072, xmod);

    // qkv: [1280][3072] @ [3072][9216] -> bf16 (direct-A)
    k_gemmA<2><<<dim3(36, 5, 1), 512, 0, stream>>>(xmod, i_qkv_w, t_qkv_w, i_qkv_b, t_qkv_b,
                                                   qkvb, 4, 9216, CC, CC);

    k_pack<<<23040, 256, 0, stream>>>(qkvb, i_qn, i_kn, t_qn, t_kn, fc, fs, qpk, kpk, vpk);

    k_attn<<<dim3(10, 24), 512, 0, stream>>>(qpk, kpk, vpk, obuf);

    // proj: obuf @ pw, split-K2 -> partials; fused reduce+residual+LN+mod
    k_gemm<3><<<dim3(24, 5, 2), 512, 0, stream>>>(obuf, i_pw, t_pw, nullptr, nullptr,
                                                  pbufP, 4, CC, CC / 2, CC);
    k_redln<<<SS, 256, 0, stream>>>(pbufP, i_pb, t_pb, mod_i + 6144, mod_t + 6144,
                                    img, txt,
                                    mod_i + 9216, mod_i + 12288,
                                    mod_t + 9216, mod_t + 12288,
                                    out_img, xmod);

    // f1: xmod @ f1w -> gelu -> hbuf bf16 (direct-A)
    k_gemmA<1><<<dim3(48, 5, 1), 512, 0, stream>>>(xmod, i_f1w, t_f1w, i_f1b, t_f1b,
                                                   hbuf, 4, MLPD, CC, CC);

    // f2: hbuf @ f2w, split-K2 -> partials, reduce in-place on d_out, gate g2
    k_gemm<3><<<dim3(24, 5, 2), 512, 0, stream>>>(hbuf, i_f2w, t_f2w, nullptr, nullptr,
                                                  pbufF, 4, CC, MLPD / 2, MLPD);
    k_red<<<3840, 256, 0, stream>>>(pbufF, i_f2b, t_f2b, mod_i + 15360, mod_t + 15360,
                                    out_img, out_txt, out_img);
}

// Round 18
// 645.862 us; speedup vs baseline: 1.4505x; 1.4505x over previous
//
#include <hip/hip_runtime.h>

// HunyuanVideoDoubleStreamBlock on MI355X (gfx950).
// Needs ws_size >= ~87 MB.

#define SI 1024
#define ST 256
#define SS 1280
#define CC 3072
#define NH 24
#define DH 128
#define MLPD 12288
#define EPSF 1e-6f
#define SCALEF 0.08838834764831845f   // 1/sqrt(128)

typedef __attribute__((ext_vector_type(4))) float f32x4;
typedef __attribute__((ext_vector_type(8))) __bf16 bf16x8;
typedef unsigned short u16;
typedef unsigned int u32;

__device__ __forceinline__ u16 f2bf(float x) {
    union { float f; u32 u; } v; v.f = x;
    u32 r = v.u + 0x7FFFu + ((v.u >> 16) & 1u);   // RNE
    return (u16)(r >> 16);
}
__device__ __forceinline__ float bf2f(u16 x) {
    union { u32 u; float f; } v; v.u = ((u32)x) << 16; return v.f;
}

// 16B-chunk swizzle (validated numerically R6-R16).
__device__ __forceinline__ int gsw(int r) {
    return ((r >> 2) & 7) ^ ((r & 3) << 1);
}

// ---------------------------------------------------------------------------
// K0: sv = silu(vec); mod = sv @ mod_w + mod_b  (both streams)
// ---------------------------------------------------------------------------
__global__ __launch_bounds__(256) void k_modvec(
    const float* __restrict__ vec,
    const float* __restrict__ wi, const float* __restrict__ bi,
    const float* __restrict__ wt, const float* __restrict__ bt,
    float* __restrict__ mi, float* __restrict__ mt)
{
    __shared__ float sv[CC];
    __shared__ float part[7][128];
    int t = threadIdx.x;
    for (int i = t; i < CC; i += 256) {
        float x = vec[i];
        sv[i] = x / (1.f + __expf(-x));
    }
    __syncthreads();
    int gc = blockIdx.x;
    int strm = gc >= 144;
    const float* W  = strm ? wt : wi;
    const float* Bv = strm ? bt : bi;
    float* out      = strm ? mt : mi;
    int c0 = (gc % 144) * 128 + 4 * (t & 31);
    int g  = t >> 5;
    const float* wp  = W + (size_t)(g * 384) * (6 * CC) + c0;
    const float* svp = sv + g * 384;
    f32x4 acc = {0.f, 0.f, 0.f, 0.f};
    for (int r = 0; r < 384; ++r) {
        f32x4 wr = *(const f32x4*)(wp + (size_t)r * (6 * CC));
        float s = svp[r];
        acc.x += wr.x * s; acc.y += wr.y * s; acc.z += wr.z * s; acc.w += wr.w * s;
    }
    int li = t & 31;
    if (g > 0) *(f32x4*)&part[g - 1][li * 4] = acc;
    __syncthreads();
    if (g == 0) {
#pragma unroll
        for (int i = 0; i < 7; ++i) {
            f32x4 p = *(const f32x4*)&part[i][li * 4];
            acc.x += p.x; acc.y += p.y; acc.z += p.z; acc.w += p.w;
        }
        f32x4 bb = *(const f32x4*)(Bv + c0);
        acc.x += bb.x; acc.y += bb.y; acc.z += bb.z; acc.w += bb.w;
        *(f32x4*)(out + c0) = acc;
    }
}

// ---------------------------------------------------------------------------
// K1: per-row LayerNorm + modulate -> bf16. Merged streams: r<SI img, else txt.
// ---------------------------------------------------------------------------
__global__ __launch_bounds__(256) void k_lnmod(
    const float* __restrict__ xi, const float* __restrict__ xt,
    const float* __restrict__ shi, const float* __restrict__ sci,
    const float* __restrict__ sht, const float* __restrict__ sct,
    u16* __restrict__ out)
{
    int r = blockIdx.x;
    bool ts = r >= SI;
    const float* xp = ts ? (xt + (size_t)(r - SI) * CC) : (xi + (size_t)r * CC);
    const float* shift = ts ? sht : shi;
    const float* scale = ts ? sct : sci;
    u16* op = out + (size_t)r * CC;
    int t = threadIdx.x;
    float4 v[3];
    float s = 0.f, q = 0.f;
#pragma unroll
    for (int j = 0; j < 3; ++j) {
        v[j] = *(const float4*)(xp + j * 1024 + t * 4);
        s += v[j].x + v[j].y + v[j].z + v[j].w;
        q += v[j].x * v[j].x + v[j].y * v[j].y + v[j].z * v[j].z + v[j].w * v[j].w;
    }
#pragma unroll
    for (int m = 32; m; m >>= 1) { s += __shfl_xor(s, m); q += __shfl_xor(q, m); }
    __shared__ float red[8];
    int w = t >> 6;
    if ((t & 63) == 0) { red[w] = s; red[4 + w] = q; }
    __syncthreads();
    s = red[0] + red[1] + red[2] + red[3];
    q = red[4] + red[5] + red[6] + red[7];
    float mean = s * (1.f / CC);
    float var  = q * (1.f / CC) - mean * mean;
    float inv  = rsqrtf(var + EPSF);
#pragma unroll
    for (int j = 0; j < 3; ++j) {
        int c0 = j * 1024 + t * 4;
        float4 sh = *(const float4*)(shift + c0);
        float4 sc = *(const float4*)(scale + c0);
        ushort4 o;
        o.x = f2bf((v[j].x - mean) * inv * (1.f + sc.x) + sh.x);
        o.y = f2bf((v[j].y - mean) * inv * (1.f + sc.y) + sh.y);
        o.z = f2bf((v[j].z - mean) * inv * (1.f + sc.z) + sh.z);
        o.w = f2bf((v[j].w - mean) * inv * (1.f + sc.w) + sh.w);
        *(ushort4*)(op + c0) = o;
    }
}

// ---------------------------------------------------------------------------
// K2: GEMM  C = A[M][lda](bf16) @ W[K][N](f32->bf16). 256xBN tile, BK=64,
// 512 threads / 8 waves. ROLLED K-loop, strength-reduced addressing,
// glds-A staging (R16-proven known-good).
//   V=0: out f32 = val+bias
//   V=1: out bf16 = gelu_tanh(val+bias)
//   V=2: out bf16 = val+bias
//   V=3: out f32 partial (at [(z*1280+row)*N+col]; bias applied in reduce)
// ---------------------------------------------------------------------------
template <int V, int BN>
__global__ __launch_bounds__(512, 2) void k_gemm(
    const u16* __restrict__ A,
    const float* __restrict__ Wi, const float* __restrict__ Wt,
    const float* __restrict__ bi, const float* __restrict__ bt,
    void* __restrict__ outv, int MBI, int N, int K, int lda)
{
    constexpr int BM  = 256;
    constexpr int NWN = (BN == 256) ? 4 : 2;
    constexpr int WM  = (BN == 256) ? 128 : 64;
    constexpr int MI  = WM / 16;
    constexpr int NFB = (BN == 256) ? 8 : 4;

    __shared__ u16 lA[2][BM * 64];
    __shared__ u16 lB[2][BN * 64];
    int t = threadIdx.x;
    int m0 = blockIdx.y * BM;
    int n0 = blockIdx.x * BN;
    bool txts = (blockIdx.y >= (unsigned)MBI);
    const float* W = txts ? Wt : Wi;
    const size_t koff = (size_t)blockIdx.z * K;

    int w = __builtin_amdgcn_readfirstlane(t >> 6);     // wave id (SGPR)
    int lane = t & 63;
    int wm = (w / NWN) * WM, wn = (w % NWN) * 64;
    int lr = lane & 15, lg = lane >> 4;

    f32x4 acc[MI][4];
#pragma unroll
    for (int i = 0; i < MI; ++i)
#pragma unroll
        for (int j = 0; j < 4; ++j) acc[i][j] = (f32x4){0.f, 0.f, 0.f, 0.f};

    const int bn4 = (BN == 256) ? 4 * (t & 63) : 4 * (t & 31);
    const int bk  = (BN == 256) ? 8 * w : 4 * (t >> 5);
    f32x4 fb[NFB];
    const int NT = K >> 6;

    const float* bptr = W + (koff + bk) * (size_t)N + n0 + bn4;
    const int arow = t >> 3;
    const int acsw = ((t & 7) ^ gsw(arow)) * 8;
    const u16* aptr = A + (size_t)(m0 + arow) * lda + koff + acsw;

    auto LOADB = [&]() {
#pragma unroll
        for (int i = 0; i < NFB; ++i)
            fb[i] = *(const f32x4*)(bptr + (size_t)i * N);
        bptr += (size_t)64 * N;
    };
    auto GLDSA = [&](int buf) {
#pragma unroll
        for (int i = 0; i < 4; ++i) {
            const u16* gp = aptr + (size_t)(i * 64) * lda;
            u16* lp = &lA[buf][(i * 512 + t) * 8];
            __builtin_amdgcn_global_load_lds(
                (const __attribute__((address_space(1))) void*)gp,
                (__attribute__((address_space(3))) void*)lp, 16, 0, 0);
        }
        aptr += 64;
    };
    auto CVTWR = [&](int buf) {
        if constexpr (BN == 256) {
#pragma unroll
            for (int j = 0; j < 4; ++j) {
                int n = bn4 + j;
                union { uint4 q; __bf16 h[8]; } u;
#pragma unroll
                for (int i = 0; i < 8; ++i) u.h[i] = (__bf16)fb[i][j];
                int cp = (bk >> 3) ^ gsw(n);
                *(uint4*)&lB[buf][n * 64 + cp * 8] = u.q;
            }
        } else {
#pragma unroll
            for (int j = 0; j < 4; ++j) {
                int n = bn4 + j;
                union { uint2 q; __bf16 h[4]; } u;
#pragma unroll
                for (int i = 0; i < 4; ++i) u.h[i] = (__bf16)fb[i][j];
                int cp = (bk >> 3) ^ gsw(n);
                *(uint2*)&lB[buf][n * 64 + cp * 8 + (bk & 4)] = u.q;
            }
        }
    };
    auto MFMAP = [&](int buf) {
#pragma unroll
        for (int ks = 0; ks < 2; ++ks) {
            bf16x8 bv[4];
#pragma unroll
            for (int j = 0; j < 4; ++j) {
                int n = wn + j * 16 + lr;
                bv[j] = *(const bf16x8*)&lB[buf][n * 64 + (((ks * 4 + lg) ^ gsw(n)) * 8)];
            }
#pragma unroll
            for (int mh = 0; mh < MI / 4; ++mh) {
                bf16x8 af[4];
#pragma unroll
                for (int i2 = 0; i2 < 4; ++i2) {
                    int m = wm + (mh * 4 + i2) * 16 + lr;
                    af[i2] = *(const bf16x8*)&lA[buf][m * 64 + (((ks * 4 + lg) ^ gsw(m)) * 8)];
                }
                __builtin_amdgcn_s_setprio(1);
#pragma unroll
                for (int i2 = 0; i2 < 4; ++i2)
#pragma unroll
                    for (int j = 0; j < 4; ++j)
                        acc[mh * 4 + i2][j] = __builtin_amdgcn_mfma_f32_16x16x32_bf16(
                            af[i2], bv[j], acc[mh * 4 + i2][j], 0, 0, 0);
                __builtin_amdgcn_s_setprio(0);
            }
        }
    };
    auto VMWN = [&]() {
        if constexpr (BN == 256)
            asm volatile("s_waitcnt vmcnt(8) lgkmcnt(0)" ::: "memory");
        else
            asm volatile("s_waitcnt vmcnt(4) lgkmcnt(0)" ::: "memory");
    };

    // ---- prologue
    LOADB();
    GLDSA(0);
    CVTWR(0);
    if (NT > 1) LOADB();
    VMWN();
    __builtin_amdgcn_s_barrier();
    __builtin_amdgcn_sched_barrier(0);

    int cur = 0;
    for (int kt = 0; kt < NT; ++kt) {
        bool s1 = kt + 1 < NT;
        bool s2 = kt + 2 < NT;
        if (s1) {
            GLDSA(cur ^ 1);
            CVTWR(cur ^ 1);
        }
        if (s2) LOADB();
        MFMAP(cur);
        if (s1) {
            if (s2) { VMWN(); }
            else    { asm volatile("s_waitcnt vmcnt(0) lgkmcnt(0)" ::: "memory"); }
            __builtin_amdgcn_s_barrier();
            __builtin_amdgcn_sched_barrier(0);
        }
        cur ^= 1;
    }

    // ---- epilogue
    const float* Bb = txts ? bt : bi;
    int MT = gridDim.y * BM;
#pragma unroll
    for (int i = 0; i < MI; ++i) {
#pragma unroll
        for (int j = 0; j < 4; ++j) {
            int col = n0 + wn + j * 16 + lr;
            float bvv = (V == 3) ? 0.f : Bb[col];
#pragma unroll
            for (int e = 0; e < 4; ++e) {
                int row = m0 + wm + i * 16 + lg * 4 + e;
                float val = acc[i][j][e] + bvv;
                if (V == 0) {
                    ((float*)outv)[(size_t)row * N + col] = val;
                } else if (V == 1) {
                    float g = 0.5f * val * (1.f + tanhf(0.7978845608028654f * (val + 0.044715f * val * val * val)));
                    ((u16*)outv)[(size_t)row * N + col] = f2bf(g);
                } else if (V == 2) {
                    ((u16*)outv)[(size_t)row * N + col] = f2bf(val);
                } else {
                    ((float*)outv)[((size_t)blockIdx.z * MT + row) * N + col] = val;
                }
            }
        }
    }
}

// ---------------------------------------------------------------------------
// K2b: split-K reduce + bias + gate + residual.  out = base + (p0+p1+b)*g
// ---------------------------------------------------------------------------
__global__ __launch_bounds__(256) void k_red(
    const float* __restrict__ p,
    const float* __restrict__ bi, const float* __restrict__ bt,
    const float* __restrict__ gi, const float* __restrict__ gt,
    const float* __restrict__ basei, const float* __restrict__ baset,
    float* __restrict__ out)
{
    int idx4 = blockIdx.x * 256 + threadIdx.x;
    size_t idx = (size_t)idx4 * 4;
    const size_t MN = (size_t)SS * CC;
    int r = idx4 / 768;
    int c = (idx4 - r * 768) * 4;
    bool ts = r >= SI;
    float4 v0 = *(const float4*)(p + idx);
    float4 v1 = *(const float4*)(p + MN + idx);
    float4 bb = *(const float4*)((ts ? bt : bi) + c);
    float4 gg = *(const float4*)((ts ? gt : gi) + c);
    const float* bp = ts ? (baset + (size_t)(r - SI) * CC + c) : (basei + (size_t)r * CC + c);
    float4 ba = *(const float4*)bp;
    float4 o;
    o.x = ba.x + (v0.x + v1.x + bb.x) * gg.x;
    o.y = ba.y + (v0.y + v1.y + bb.y) * gg.y;
    o.z = ba.z + (v0.z + v1.z + bb.z) * gg.z;
    o.w = ba.w + (v0.w + v1.w + bb.w) * gg.w;
    *(float4*)(out + idx) = o;
}

// ---------------------------------------------------------------------------
// K2c: split-K reduce + bias + gate + residual, FUSED with LayerNorm+mod.
// ---------------------------------------------------------------------------
__global__ __launch_bounds__(256) void k_redln(
    const float* __restrict__ p,
    const float* __restrict__ bi, const float* __restrict__ bt,
    const float* __restrict__ gi, const float* __restrict__ gt,
    const float* __restrict__ basei, const float* __restrict__ baset,
    const float* __restrict__ shi, const float* __restrict__ sci,
    const float* __restrict__ sht, const float* __restrict__ sct,
    float* __restrict__ out, u16* __restrict__ xm)
{
    int r = blockIdx.x;
    int t = threadIdx.x;
    bool ts = r >= SI;
    const size_t MN = (size_t)SS * CC;
    const float* b  = ts ? bt : bi;
    const float* g  = ts ? gt : gi;
    const float* base = ts ? (baset + (size_t)(r - SI) * CC) : (basei + (size_t)r * CC);
    const float* p0 = p + (size_t)r * CC;
    const float* p1 = p0 + MN;
    float* op = out + (size_t)r * CC;
    u16*   xp = xm + (size_t)r * CC;

    float4 v[3];
    float s = 0.f, q = 0.f;
#pragma unroll
    for (int j = 0; j < 3; ++j) {
        int c0 = j * 1024 + t * 4;
        float4 a0 = *(const float4*)(p0 + c0);
        float4 a1 = *(const float4*)(p1 + c0);
        float4 bb = *(const float4*)(b + c0);
        float4 gg = *(const float4*)(g + c0);
        float4 ba = *(const float4*)(base + c0);
        float4 o;
        o.x = ba.x + (a0.x + a1.x + bb.x) * gg.x;
        o.y = ba.y + (a0.y + a1.y + bb.y) * gg.y;
        o.z = ba.z + (a0.z + a1.z + bb.z) * gg.z;
        o.w = ba.w + (a0.w + a1.w + bb.w) * gg.w;
        *(float4*)(op + c0) = o;
        v[j] = o;
        s += o.x + o.y + o.z + o.w;
        q += o.x * o.x + o.y * o.y + o.z * o.z + o.w * o.w;
    }
#pragma unroll
    for (int m = 32; m; m >>= 1) { s += __shfl_xor(s, m); q += __shfl_xor(q, m); }
    __shared__ float red[8];
    int w = t >> 6;
    if ((t & 63) == 0) { red[w] = s; red[4 + w] = q; }
    __syncthreads();
    s = red[0] + red[1] + red[2] + red[3];
    q = red[4] + red[5] + red[6] + red[7];
    float mean = s * (1.f / CC);
    float var  = q * (1.f / CC) - mean * mean;
    float inv  = rsqrtf(var + EPSF);
    const float* sh = ts ? sht : shi;
    const float* sc = ts ? sct : sci;
#pragma unroll
    for (int j = 0; j < 3; ++j) {
        int c0 = j * 1024 + t * 4;
        float4 shv = *(const float4*)(sh + c0);
        float4 scv = *(const float4*)(sc + c0);
        ushort4 o;
        o.x = f2bf((v[j].x - mean) * inv * (1.f + scv.x) + shv.x);
        o.y = f2bf((v[j].y - mean) * inv * (1.f + scv.y) + shv.y);
        o.z = f2bf((v[j].z - mean) * inv * (1.f + scv.z) + shv.z);
        o.w = f2bf((v[j].w - mean) * inv * (1.f + scv.w) + shv.w);
        *(ushort4*)(xp + c0) = o;
    }
}

// ---------------------------------------------------------------------------
// K3: qkv epilogue: RMSNorm(q,k)+RoPE(img)+scale(q), pack to [h][s][d] bf16.
// ---------------------------------------------------------------------------
__global__ __launch_bounds__(256) void k_pack(
    const u16* __restrict__ qkv,
    const float* __restrict__ iqn, const float* __restrict__ ikn,
    const float* __restrict__ tqn, const float* __restrict__ tkn,
    const float* __restrict__ fc, const float* __restrict__ fs,
    u16* __restrict__ qpk, u16* __restrict__ kpk, u16* __restrict__ vpk)
{
    int wid = blockIdx.x * 4 + (threadIdx.x >> 6);
    int lane = threadIdx.x & 63;
    int s = wid / 72;
    int wh = wid % 72;
    int which = wh / 24;
    int h = wh % 24;
    int d = lane * 2;
    const u16* src = qkv + (size_t)s * 9216 + which * 3072 + h * 128 + d;
    ushort2 xv = *(const ushort2*)src;
    float x0 = bf2f(xv.x), x1 = bf2f(xv.y);
    float y0 = x0, y1 = x1;
    if (which < 2) {
        float ssq = x0 * x0 + x1 * x1;
#pragma unroll
        for (int m = 32; m; m >>= 1) ssq += __shfl_xor(ssq, m);
        float inv = rsqrtf(ssq * (1.f / 128.f) + EPSF);
        bool isimg = (s < SI);
        const float* wv = (which == 0) ? (isimg ? iqn : tqn) : (isimg ? ikn : tkn);
        y0 = x0 * inv * wv[d];
        y1 = x1 * inv * wv[d + 1];
        if (isimg) {
            float c0 = fc[s * 128 + d], c1 = fc[s * 128 + d + 1];
            float s0 = fs[s * 128 + d], s1 = fs[s * 128 + d + 1];
            float r0 = y0 * c0 - y1 * s0;
            float r1 = y1 * c1 + y0 * s1;
            y0 = r0; y1 = r1;
        }
        if (which == 0) { y0 *= SCALEF; y1 *= SCALEF; }
    }
    u16* dst = (which == 0) ? qpk : (which == 1) ? kpk : vpk;
    ushort2 o; o.x = f2bf(y0); o.y = f2bf(y1);
    *(ushort2*)(dst + ((size_t)h * SS + s) * 128 + d) = o;
}

// ---------------------------------------------------------------------------
// K4: flash attention. grid (10 q-tiles, 24 heads) x 512 (8 waves, 16 q/wave).
// V^T staged via pair-transpose into chunk-XOR-swizzled layout.
// ---------------------------------------------------------------------------
__global__ __launch_bounds__(512, 1) void k_attn(
    const u16* __restrict__ qpk, const u16* __restrict__ kpk,
    const u16* __restrict__ vpk, u16* __restrict__ o)
{
    __shared__ u16 lK[128 * 136];
    __shared__ u16 lV[128 * 136];
    __shared__ u16 lP[128 * 136];
    int h = blockIdx.y;
    int q0 = blockIdx.x * 128;
    int t = threadIdx.x, w = t >> 6, lane = t & 63;
    int lr = lane & 15, lg = lane >> 4;
    const u16* qh = qpk + (size_t)h * SS * 128;
    const u16* kh = kpk + (size_t)h * SS * 128;
    const u16* vh = vpk + (size_t)h * SS * 128;

    bf16x8 aq[4];
#pragma unroll
    for (int kk = 0; kk < 4; ++kk)
        aq[kk] = *(const bf16x8*)(qh + (size_t)(q0 + w * 16 + lr) * 128 + kk * 32 + lg * 8);

    const f32x4 fz = {0.f, 0.f, 0.f, 0.f};
    f32x4 oa[8];
#pragma unroll
    for (int j = 0; j < 8; ++j) oa[j] = fz;
    float mrow[4], lrow[4];
#pragma unroll
    for (int e = 0; e < 4; ++e) { mrow[e] = -1e30f; lrow[e] = 0.f; }

    for (int kt = 0; kt < 10; ++kt) {
        int t0 = kt * 128;
        __syncthreads();
#pragma unroll
        for (int it = 0; it < 4; ++it) {
            int c = it * 512 + t;
            int row = c >> 4, part = c & 15;
            uint4 d4 = *(const uint4*)(kh + (size_t)(t0 + row) * 128 + part * 8);
            *(uint4*)(&lK[row * 136 + part * 8]) = d4;
        }
#pragma unroll
        for (int it = 0; it < 2; ++it) {
            int c = it * 512 + t;
            int pr = c >> 4;
            int tt = pr * 2;
            int k = c & 15;
            int d0 = k * 8;
            uint4 a = *(const uint4*)(vh + (size_t)(t0 + tt) * 128 + d0);
            uint4 b = *(const uint4*)(vh + (size_t)(t0 + tt + 1) * 128 + d0);
            const u16* a16 = (const u16*)&a;
            const u16* b16 = (const u16*)&b;
            int ts = tt ^ ((k & 7) << 3);
#pragma unroll
            for (int j = 0; j < 8; ++j) {
                ushort2 pv; pv.x = a16[j]; pv.y = b16[j];
                *(ushort2*)(&lV[(d0 + j) * 136 + ts]) = pv;
            }
        }
        __syncthreads();
        f32x4 sa[8];
#pragma unroll
        for (int j = 0; j < 8; ++j) sa[j] = fz;
#pragma unroll
        for (int kk = 0; kk < 4; ++kk) {
            bf16x8 bk[8];
#pragma unroll
            for (int ni = 0; ni < 8; ++ni)
                bk[ni] = *(const bf16x8*)(&lK[(ni * 16 + lr) * 136 + kk * 32 + lg * 8]);
            __builtin_amdgcn_s_setprio(1);
#pragma unroll
            for (int ni = 0; ni < 8; ++ni)
                sa[ni] = __builtin_amdgcn_mfma_f32_16x16x32_bf16(aq[kk], bk[ni], sa[ni], 0, 0, 0);
            __builtin_amdgcn_s_setprio(0);
        }
#pragma unroll
        for (int e = 0; e < 4; ++e) {
            float mx = sa[0][e];
#pragma unroll
            for (int ni = 1; ni < 8; ++ni) mx = fmaxf(mx, sa[ni][e]);
#pragma unroll
            for (int msk = 1; msk < 16; msk <<= 1) mx = fmaxf(mx, __shfl_xor(mx, msk));
            float mnew = fmaxf(mrow[e], mx);
            float esc = __expf(mrow[e] - mnew);
            mrow[e] = mnew;
            float rsum = 0.f;
#pragma unroll
            for (int ni = 0; ni < 8; ++ni) {
                float p = __expf(sa[ni][e] - mnew);
                sa[ni][e] = p;
                rsum += p;
            }
#pragma unroll
            for (int msk = 1; msk < 16; msk <<= 1) rsum += __shfl_xor(rsum, msk);
            lrow[e] = lrow[e] * esc + rsum;
#pragma unroll
            for (int nd = 0; nd < 8; ++nd) oa[nd][e] *= esc;
        }
#pragma unroll
        for (int ni = 0; ni < 8; ++ni)
#pragma unroll
            for (int e = 0; e < 4; ++e)
                lP[(w * 16 + lg * 4 + e) * 136 + ni * 16 + lr] = f2bf(sa[ni][e]);
#pragma unroll
        for (int kk = 0; kk < 4; ++kk) {
            bf16x8 pa, vb[8];
            pa = *(const bf16x8*)(&lP[(w * 16 + lr) * 136 + kk * 32 + lg * 8]);
#pragma unroll
            for (int nd = 0; nd < 8; ++nd) {
                int d = nd * 16 + lr;
                int ch = (kk * 4 + lg) ^ ((d >> 3) & 7);
                vb[nd] = *(const bf16x8*)(&lV[d * 136 + ch * 8]);
            }
            __builtin_amdgcn_s_setprio(1);
#pragma unroll
            for (int nd = 0; nd < 8; ++nd)
                oa[nd] = __builtin_amdgcn_mfma_f32_16x16x32_bf16(pa, vb[nd], oa[nd], 0, 0, 0);
            __builtin_amdgcn_s_setprio(0);
        }
    }
#pragma unroll
    for (int nd = 0; nd < 8; ++nd) {
#pragma unroll
        for (int e = 0; e < 4; ++e) {
            int row = q0 + w * 16 + lg * 4 + e;
            int col = h * 128 + nd * 16 + lr;
            o[(size_t)row * CC + col] = f2bf(oa[nd][e] / lrow[e]);
        }
    }
}

// ---------------------------------------------------------------------------
extern "C" void kernel_launch(void* const* d_in, const int* in_sizes, int n_in,
                              void* d_out, int out_size, void* d_ws, size_t ws_size,
                              hipStream_t stream)
{
    const float* img  = (const float*)d_in[0];
    const float* txt  = (const float*)d_in[1];
    const float* vec  = (const float*)d_in[2];
    const float* fc   = (const float*)d_in[3];
    const float* fs   = (const float*)d_in[4];
    const float* i_mod_w = (const float*)d_in[5];
    const float* i_mod_b = (const float*)d_in[6];
    const float* i_qkv_w = (const float*)d_in[7];
    const float* i_qkv_b = (const float*)d_in[8];
    const float* i_qn  = (const float*)d_in[9];
    const float* i_kn  = (const float*)d_in[10];
    const float* i_pw  = (const float*)d_in[11];
    const float* i_pb  = (const float*)d_in[12];
    const float* i_f1w = (const float*)d_in[13];
    const float* i_f1b = (const float*)d_in[14];
    const float* i_f2w = (const float*)d_in[15];
    const float* i_f2b = (const float*)d_in[16];
    const float* t_mod_w = (const float*)d_in[17];
    const float* t_mod_b = (const float*)d_in[18];
    const float* t_qkv_w = (const float*)d_in[19];
    const float* t_qkv_b = (const float*)d_in[20];
    const float* t_qn  = (const float*)d_in[21];
    const float* t_kn  = (const float*)d_in[22];
    const float* t_pw  = (const float*)d_in[23];
    const float* t_pb  = (const float*)d_in[24];
    const float* t_f1w = (const float*)d_in[25];
    const float* t_f1b = (const float*)d_in[26];
    const float* t_f2w = (const float*)d_in[27];
    const float* t_f2b = (const float*)d_in[28];

    char* ws = (char*)d_ws;
    float* mod_i = (float*)(ws + 0);                 // 6*3072 f32
    float* mod_t = (float*)(ws + 73728);
    u16*   xmod  = (u16*)(ws + 147456);              // [1280][3072] bf16
    u16*   qkvb  = (u16*)(ws + 8011776);             // [1280][9216] bf16
    u16*   qpk   = (u16*)(ws + 55197696);            // [24][1280][128] bf16
    u16*   kpk   = (u16*)(ws + 63062016);
    u16*   vpk   = (u16*)(ws + 70926336);
    u16*   obuf  = (u16*)(ws + 78790656);            // [1280][3072] bf16
    u16*   hbuf  = (u16*)(ws + 8011776);             // reuse qkvb: [1280][12288] bf16
    float* pbufP = (float*)(ws + 8011776);           // proj partials [2][1280][3072] f32
    float* pbufF = (float*)(ws + 39469056);          // f2 partials   [2][1280][3072] f32

    float* out_img = (float*)d_out;
    float* out_txt = out_img + (size_t)SI * CC;

    k_modvec<<<288, 256, 0, stream>>>(vec, i_mod_w, i_mod_b, t_mod_w, t_mod_b, mod_i, mod_t);

    k_lnmod<<<SS, 256, 0, stream>>>(img, txt, mod_i + 0, mod_i + 3072,
                                    mod_t + 0, mod_t + 3072, xmod);

    // qkv: [1280][3072] @ [3072][9216] -> bf16 (V=2)
    k_gemm<2, 256><<<dim3(36, 5, 1), 512, 0, stream>>>(xmod, i_qkv_w, t_qkv_w, i_qkv_b, t_qkv_b,
                                                       qkvb, 4, 9216, CC, CC);

    k_pack<<<23040, 256, 0, stream>>>(qkvb, i_qn, i_kn, t_qn, t_kn, fc, fs, qpk, kpk, vpk);

    k_attn<<<dim3(10, 24), 512, 0, stream>>>(qpk, kpk, vpk, obuf);

    // proj: obuf @ pw, split-K2 -> partials; fused reduce+residual+LN+mod
    k_gemm<3, 128><<<dim3(24, 5, 2), 512, 0, stream>>>(obuf, i_pw, t_pw, nullptr, nullptr,
                                                       pbufP, 4, CC, CC / 2, CC);
    k_redln<<<SS, 256, 0, stream>>>(pbufP, i_pb, t_pb, mod_i + 6144, mod_t + 6144,
                                    img, txt,
                                    mod_i + 9216, mod_i + 12288,
                                    mod_t + 9216, mod_t + 12288,
                                    out_img, xmod);

    // f1: xmod @ f1w -> gelu -> hbuf bf16
    k_gemm<1, 256><<<dim3(48, 5, 1), 512, 0, stream>>>(xmod, i_f1w, t_f1w, i_f1b, t_f1b,
                                                       hbuf, 4, MLPD, CC, CC);

    // f2: hbuf @ f2w, split-K2 -> partials, reduce in-place on d_out, gate g2
    k_gemm<3, 128><<<dim3(24, 5, 2), 512, 0, stream>>>(hbuf, i_f2w, t_f2w, nullptr, nullptr,
                                                       pbufF, 4, CC, MLPD / 2, MLPD);
    k_red<<<3840, 256, 0, stream>>>(pbufF, i_f2b, t_f2b, mod_i + 15360, mod_t + 15360,
                                    out_img, out_txt, out_img);
}